// Round 3
// baseline (53.626 us; speedup 1.0000x reference)
//
#include <hip/hip_runtime.h>

#define IN_F    4096
#define OUT_F   11008
#define NGROUP  512        // IN_F / 8
#define CHUNK   16         // groups per thread per block
#define NCHUNK  (NGROUP / CHUNK)   // 32
#define OTILES  (OUT_F / 256)      // 43
#define BATCH   4

typedef int   iv4 __attribute__((ext_vector_type(4)));
typedef float fv4 __attribute__((ext_vector_type(4)));

// out[b][o] = bias[o]
__global__ __launch_bounds__(256) void init_out_kernel(
    const float* __restrict__ bias, float* __restrict__ out)
{
    const int o = blockIdx.x * 256 + threadIdx.x;          // 43*256 = 11008 exactly
    out[(size_t)blockIdx.y * OUT_F + o] = bias[o];
}

// Each thread: one output o, CHUNK consecutive groups starting at g0.
// Strategy: issue ALL 16 random 32-B codebook gathers before consuming any
// (128 VGPRs of load buffer) -> ~16 loads in flight per wave to hide L2 latency.
__global__ __launch_bounds__(256) void aqlm_kernel(
    const float* __restrict__ x,        // [4][4096]
    const float* __restrict__ cb,       // [65536][8]
    const int*   __restrict__ codes,    // [11008][512]
    const float* __restrict__ scales,   // [11008]
    float*       __restrict__ out)      // [4][11008]
{
    const int o  = blockIdx.x * 256 + threadIdx.x;
    const int g0 = blockIdx.y * CHUNK;

    // This lane's 16 codes: exactly one fully-used 64-B cache line.
    // Nontemporal: the 22.5 MB code stream must not evict the L2-resident codebook.
    int code[CHUNK];
    const iv4* cp = (const iv4*)(codes + (size_t)o * NGROUP + g0);
#pragma unroll
    for (int j = 0; j < CHUNK / 4; ++j) {
        const iv4 c = __builtin_nontemporal_load(cp + j);
        code[4 * j + 0] = c.x;
        code[4 * j + 1] = c.y;
        code[4 * j + 2] = c.z;
        code[4 * j + 3] = c.w;
    }

    // Phase 1: issue all 32 dwordx4 gathers (static indexing -> registers).
    fv4 w0[CHUNK], w1[CHUNK];
#pragma unroll
    for (int j = 0; j < CHUNK; ++j) {
        const fv4* e = (const fv4*)(cb + (size_t)(unsigned)code[j] * 8u);
        w0[j] = e[0];
        w1[j] = e[1];
    }

    // Phase 2: FMA. x slices are wave-uniform -> scalar loads, L1/sL1-resident.
    float acc[BATCH];
#pragma unroll
    for (int b = 0; b < BATCH; ++b) acc[b] = 0.f;

#pragma unroll
    for (int j = 0; j < CHUNK; ++j) {
        const float* xg = x + (size_t)(g0 + j) * 8;
#pragma unroll
        for (int b = 0; b < BATCH; ++b) {
            const float* xb = xg + b * IN_F;
            acc[b] += xb[0] * w0[j].x + xb[1] * w0[j].y
                    + xb[2] * w0[j].z + xb[3] * w0[j].w
                    + xb[4] * w1[j].x + xb[5] * w1[j].y
                    + xb[6] * w1[j].z + xb[7] * w1[j].w;
        }
    }

    const float s = scales[o];
    atomicAdd(out + 0 * (size_t)OUT_F + o, s * acc[0]);
    atomicAdd(out + 1 * (size_t)OUT_F + o, s * acc[1]);
    atomicAdd(out + 2 * (size_t)OUT_F + o, s * acc[2]);
    atomicAdd(out + 3 * (size_t)OUT_F + o, s * acc[3]);
}

extern "C" void kernel_launch(void* const* d_in, const int* in_sizes, int n_in,
                              void* d_out, int out_size, void* d_ws, size_t ws_size,
                              hipStream_t stream) {
    const float* x      = (const float*)d_in[0];   // (4, 4096)
    const float* cb     = (const float*)d_in[1];   // (1, 65536, 1, 8)
    const int*   codes  = (const int*)d_in[2];     // (11008, 512, 1)
    const float* scales = (const float*)d_in[3];   // (11008, 1, 1, 1)
    const float* bias   = (const float*)d_in[4];   // (11008,)
    float* out = (float*)d_out;                    // (4, 11008)

    hipLaunchKernelGGL(init_out_kernel, dim3(OTILES, BATCH), dim3(256), 0, stream,
                       bias, out);
    hipLaunchKernelGGL(aqlm_kernel, dim3(OTILES, NCHUNK), dim3(256), 0, stream,
                       x, cb, codes, scales, out);
}

// Round 4
// 43.807 us; speedup vs baseline: 1.2241x; 1.2241x over previous
//
#include <hip/hip_runtime.h>

#define IN_F    4096
#define OUT_F   11008
#define NGROUP  512        // IN_F / 8
#define CHUNK   16         // groups per thread per block
#define NCHUNK  (NGROUP / CHUNK)   // 32
#define OTILES  (OUT_F / 256)      // 43
#define BATCH   4

typedef int   iv4 __attribute__((ext_vector_type(4)));
typedef float fv4 __attribute__((ext_vector_type(4)));

// out[b][o] = bias[o]
__global__ __launch_bounds__(256) void init_out_kernel(
    const float* __restrict__ bias, float* __restrict__ out)
{
    const int o = blockIdx.x * 256 + threadIdx.x;          // 43*256 = 11008 exactly
    out[(size_t)blockIdx.y * OUT_F + o] = bias[o];
}

// Each thread: one output o, CHUNK consecutive groups starting at g0.
// All 32 random dwordx4 gathers are issued BEFORE any FMA consumes them,
// pinned with sched_barrier(0) so the compiler cannot sink the loads.
// ~16 gathers in flight per wave hides the ~200-cyc L2 gather latency.
__global__ __launch_bounds__(256) void aqlm_kernel(
    const float* __restrict__ x,        // [4][4096]
    const float* __restrict__ cb,       // [65536][8]
    const int*   __restrict__ codes,    // [11008][512]
    const float* __restrict__ scales,   // [11008]
    float*       __restrict__ out)      // [4][11008]
{
    const int o  = blockIdx.x * 256 + threadIdx.x;
    const int g0 = blockIdx.y * CHUNK;

    // This lane's 16 codes: one fully-used 64-B cache line (plain loads —
    // nt made the 4 reads of the shared line miss: FETCH 31.5->45 MB in R3).
    int code[CHUNK];
    const iv4* cp = (const iv4*)(codes + (size_t)o * NGROUP + g0);
#pragma unroll
    for (int j = 0; j < CHUNK / 4; ++j) {
        const iv4 c = cp[j];
        code[4 * j + 0] = c.x;
        code[4 * j + 1] = c.y;
        code[4 * j + 2] = c.z;
        code[4 * j + 3] = c.w;
    }

    // Phase 1: issue all 32 dwordx4 gathers into registers.
    fv4 w0[CHUNK], w1[CHUNK];
#pragma unroll
    for (int j = 0; j < CHUNK; ++j) {
        const fv4* e = (const fv4*)(cb + (size_t)(unsigned)code[j] * 8u);
        w0[j] = e[0];
        w1[j] = e[1];
    }

    // Pin: no FMA may be hoisted above, no load may be sunk below.
    __builtin_amdgcn_sched_barrier(0);

    // Phase 2: FMA. x slices are wave-uniform -> scalar loads.
    float acc[BATCH];
#pragma unroll
    for (int b = 0; b < BATCH; ++b) acc[b] = 0.f;

#pragma unroll
    for (int j = 0; j < CHUNK; ++j) {
        const float* xg = x + (size_t)(g0 + j) * 8;
#pragma unroll
        for (int b = 0; b < BATCH; ++b) {
            const float* xb = xg + b * IN_F;
            acc[b] += xb[0] * w0[j].x + xb[1] * w0[j].y
                    + xb[2] * w0[j].z + xb[3] * w0[j].w
                    + xb[4] * w1[j].x + xb[5] * w1[j].y
                    + xb[6] * w1[j].z + xb[7] * w1[j].w;
        }
    }

    const float s = scales[o];
    atomicAdd(out + 0 * (size_t)OUT_F + o, s * acc[0]);
    atomicAdd(out + 1 * (size_t)OUT_F + o, s * acc[1]);
    atomicAdd(out + 2 * (size_t)OUT_F + o, s * acc[2]);
    atomicAdd(out + 3 * (size_t)OUT_F + o, s * acc[3]);
}

extern "C" void kernel_launch(void* const* d_in, const int* in_sizes, int n_in,
                              void* d_out, int out_size, void* d_ws, size_t ws_size,
                              hipStream_t stream) {
    const float* x      = (const float*)d_in[0];   // (4, 4096)
    const float* cb     = (const float*)d_in[1];   // (1, 65536, 1, 8)
    const int*   codes  = (const int*)d_in[2];     // (11008, 512, 1)
    const float* scales = (const float*)d_in[3];   // (11008, 1, 1, 1)
    const float* bias   = (const float*)d_in[4];   // (11008,)
    float* out = (float*)d_out;                    // (4, 11008)

    hipLaunchKernelGGL(init_out_kernel, dim3(OTILES, BATCH), dim3(256), 0, stream,
                       bias, out);
    hipLaunchKernelGGL(aqlm_kernel, dim3(OTILES, NCHUNK), dim3(256), 0, stream,
                       x, cb, codes, scales, out);
}